// Round 10
// baseline (452.872 us; speedup 1.0000x reference)
//
#include <hip/hip_runtime.h>

#define NU 100000
#define NI 50000
#define NE 819200
#define FIN 128
#define HH 32
#define CHUNK 1024

#define G_PU  3125      // NU/32
#define G_PI  1563      // ceil(NI/32)
#define G_FILL 800      // NE/4/256
#define G_P0I 6250      // NI/8
#define G_P0U 12500     // NU/8

// hist: 16384 nodes per range (32KB packed 16-bit LDS), 50 chunks of 16384 edges
#define HRNG 16384
#define HNCH 50
#define HC4  4096       // int4 per chunk
#define G_HU 350        // 7 ranges * 50 chunks
#define G_HI 200        // 4 ranges * 50 chunks

// ================= histogram degree count =================
__global__ __launch_bounds__(1024) void hist_k(const int4* __restrict__ eu4,
                                               const int4* __restrict__ ei4,
                                               int* __restrict__ curU,
                                               int* __restrict__ curI) {
    __shared__ unsigned sh[HRNG / 2];   // 8192 words = 16384 packed u16 counters
    int tid = threadIdx.x;
    int b = blockIdx.x;
    const int4* E;
    int* cur;
    int lo, N, chunk;
    if (b < G_HU) {
        E = eu4; cur = curU; N = NU;
        lo = (b / HNCH) * HRNG; chunk = b % HNCH;
    } else {
        int bb = b - G_HU;
        E = ei4; cur = curI; N = NI;
        lo = (bb / HNCH) * HRNG; chunk = bb % HNCH;
    }
    for (int i = tid; i < HRNG / 2; i += 1024) sh[i] = 0u;
    __syncthreads();
    int base = chunk * HC4;
#pragma unroll
    for (int it = 0; it < HC4 / 1024; ++it) {
        int4 v = E[base + it * 1024 + tid];
        int d;
        d = v.x - lo; if ((unsigned)d < (unsigned)HRNG) atomicAdd(&sh[d >> 1], (d & 1) ? 65536u : 1u);
        d = v.y - lo; if ((unsigned)d < (unsigned)HRNG) atomicAdd(&sh[d >> 1], (d & 1) ? 65536u : 1u);
        d = v.z - lo; if ((unsigned)d < (unsigned)HRNG) atomicAdd(&sh[d >> 1], (d & 1) ? 65536u : 1u);
        d = v.w - lo; if ((unsigned)d < (unsigned)HRNG) atomicAdd(&sh[d >> 1], (d & 1) ? 65536u : 1u);
    }
    __syncthreads();
    for (int i = tid; i < HRNG / 2; i += 1024) {
        unsigned w = sh[i];
        if (w) {
            int n0 = lo + 2 * i;
            unsigned c0 = w & 0xFFFFu, c1 = w >> 16;
            if (c0 && n0 < N) atomicAdd(cur + n0, (int)c0);
            if (c1 && n0 + 1 < N) atomicAdd(cur + n0 + 1, (int)c1);
        }
    }
}

// ================= scans =================
__global__ void scanA_k(const int* __restrict__ src, int n,
                        int* __restrict__ dst, int* __restrict__ part) {
    __shared__ int ts[256];
    int t = threadIdx.x, b = blockIdx.x;
    int base = b * CHUNK + t * 4;
    int v0 = 0, v1 = 0, v2 = 0, v3 = 0;
    if (base + 0 < n) v0 = src[base + 0];
    if (base + 1 < n) v1 = src[base + 1];
    if (base + 2 < n) v2 = src[base + 2];
    if (base + 3 < n) v3 = src[base + 3];
    int s = v0 + v1 + v2 + v3;
    ts[t] = s;
    __syncthreads();
    int incl = s;
    for (int off = 1; off < 256; off <<= 1) {
        int y = (t >= off) ? ts[t - off] : 0;
        __syncthreads();
        incl += y;
        ts[t] = incl;
        __syncthreads();
    }
    if (t == 255) part[b] = incl;
    int r = incl - s;
    if (base + 0 < n) dst[base + 0] = r; r += v0;
    if (base + 1 < n) dst[base + 1] = r; r += v1;
    if (base + 2 < n) dst[base + 2] = r; r += v2;
    if (base + 3 < n) dst[base + 3] = r;
}

__global__ void scanB_k(int* __restrict__ pU, int nU, int* __restrict__ pI, int nI) {
    __shared__ int ts[256];
    int t = threadIdx.x;
    for (int a = 0; a < 2; ++a) {
        int* p = a ? pI : pU;
        int nb = a ? nI : nU;
        int v = (t < nb) ? p[t] : 0;
        ts[t] = v;
        __syncthreads();
        int incl = v;
        for (int off = 1; off < 256; off <<= 1) {
            int y = (t >= off) ? ts[t - off] : 0;
            __syncthreads();
            incl += y;
            ts[t] = incl;
            __syncthreads();
        }
        if (t < nb) p[t] = incl - v;
        __syncthreads();
    }
}

__global__ void scanC_k(int* __restrict__ rs, const int* __restrict__ part, int n,
                        int* __restrict__ cur) {
    int i = blockIdx.x * 256 + threadIdx.x;
    if (i < n) {
        int v = rs[i] + part[i >> 10];
        rs[i] = v;
        cur[i] = v;
    } else if (i == n) {
        rs[n] = NE;
    }
}

// ================= CSR fill (both directions, proven round-8 form) =================
__global__ void fill_k(const int4* __restrict__ eu4, const int4* __restrict__ ei4,
                       int* __restrict__ curU, int* __restrict__ curI,
                       int* __restrict__ csrU, int* __restrict__ csrI) {
    int t = blockIdx.x * 256 + threadIdx.x;
    int4 u = eu4[t];
    int4 i = ei4[t];
    int a0 = atomicAdd(curI + i.x, 1);
    int a1 = atomicAdd(curI + i.y, 1);
    int a2 = atomicAdd(curI + i.z, 1);
    int a3 = atomicAdd(curI + i.w, 1);
    int b0 = atomicAdd(curU + u.x, 1);
    int b1 = atomicAdd(curU + u.y, 1);
    int b2 = atomicAdd(curU + u.z, 1);
    int b3 = atomicAdd(curU + u.w, 1);
    csrI[a0] = u.x;
    csrI[a1] = u.y;
    csrI[a2] = u.z;
    csrI[a3] = u.w;
    csrU[b0] = i.x;
    csrU[b1] = i.y;
    csrU[b2] = i.z;
    csrU[b3] = i.w;
}

// ================= device bodies =================

__device__ __forceinline__ void proj128_body(const float* __restrict__ X,
                                             const float* __restrict__ Wl,
                                             const float* __restrict__ Wr,
                                             float* __restrict__ S, float* __restrict__ R,
                                             int N, int vb, float* smem) {
    float* sWlT = smem;
    float* sWrT = smem + FIN * 33;
    float* sX   = smem + 2 * FIN * 33;
    int tid = threadIdx.x;
    {
        float4 a = ((const float4*)Wl)[tid];
        float4 b = ((const float4*)Wr)[tid];
        int e0 = tid * 4;
        int o = e0 >> 7, k = e0 & 127;
        sWlT[(k + 0) * 33 + o] = a.x;
        sWlT[(k + 1) * 33 + o] = a.y;
        sWlT[(k + 2) * 33 + o] = a.z;
        sWlT[(k + 3) * 33 + o] = a.w;
        sWrT[(k + 0) * 33 + o] = b.x;
        sWrT[(k + 1) * 33 + o] = b.y;
        sWrT[(k + 2) * 33 + o] = b.z;
        sWrT[(k + 3) * 33 + o] = b.w;
    }
    int n0 = vb * 32;
    int n = tid >> 5, c = tid & 31;
    if (n0 + n < N) {
        int k4 = c * 4;
        float4 v = *(const float4*)(X + (size_t)(n0 + n) * FIN + k4);
        sX[n * 129 + k4 + 0] = v.x;
        sX[n * 129 + k4 + 1] = v.y;
        sX[n * 129 + k4 + 2] = v.z;
        sX[n * 129 + k4 + 3] = v.w;
    }
    __syncthreads();
    if (n0 + n < N) {
        float aL = 0.f, aR = 0.f;
#pragma unroll
        for (int k = 0; k < FIN; ++k) {
            float x = sX[n * 129 + k];
            aL += x * sWlT[k * 33 + c];
            aR += x * sWrT[k * 33 + c];
        }
        S[(size_t)(n0 + n) * HH + c] = aL;
        R[(size_t)(n0 + n) * HH + c] = aR;
    }
}

__device__ __forceinline__ void proj32_body(const float* __restrict__ X,
                                            const float* __restrict__ Wl,
                                            const float* __restrict__ Wr,
                                            float* __restrict__ S, float* __restrict__ R,
                                            int vb, float* smem) {
    float* sWlT = smem;
    float* sWrT = smem + HH * 33;
    float* sX   = smem + 2 * HH * 33;
    int tid = threadIdx.x;
    {
        float4 a = ((const float4*)Wl)[tid];
        float4 b = ((const float4*)Wr)[tid];
        int e0 = tid * 4;
        int o = e0 >> 5, k = e0 & 31;
        sWlT[(k + 0) * 33 + o] = a.x;
        sWlT[(k + 1) * 33 + o] = a.y;
        sWlT[(k + 2) * 33 + o] = a.z;
        sWlT[(k + 3) * 33 + o] = a.w;
        sWrT[(k + 0) * 33 + o] = b.x;
        sWrT[(k + 1) * 33 + o] = b.y;
        sWrT[(k + 2) * 33 + o] = b.z;
        sWrT[(k + 3) * 33 + o] = b.w;
    }
    int n0 = vb * 8;
    int n = tid >> 5, c = tid & 31;
    sX[n * 33 + c] = X[(size_t)(n0 + n) * HH + c];
    __syncthreads();
    float aL = 0.f, aR = 0.f;
#pragma unroll
    for (int k = 0; k < HH; ++k) {
        float x = sX[n * 33 + k];
        aL += x * sWlT[k * 33 + c];
        aR += x * sWrT[k * 33 + c];
    }
    S[(size_t)(n0 + n) * HH + c] = aL;
    R[(size_t)(n0 + n) * HH + c] = aR;
}

__device__ __forceinline__ void pull0_body(const int* __restrict__ csr,
                                           const int* __restrict__ rs,
                                           const float* __restrict__ S,
                                           float* __restrict__ R,
                                           const float* __restrict__ bias, int vb) {
    int tid = threadIdx.x;
    int n = vb * 8 + (tid >> 5);
    int c = tid & 31;
    int s0 = rs[n], s1 = rs[n + 1];
    float acc = 0.f, acc2 = 0.f;
    int j = s0;
    for (; j + 1 < s1; j += 2) {
        int a = csr[j], b = csr[j + 1];
        acc  += S[(size_t)a * HH + c];
        acc2 += S[(size_t)b * HH + c];
    }
    if (j < s1) acc += S[(size_t)csr[j] * HH + c];
    acc += acc2;
    float deg = (float)(s1 - s0);
    deg = deg > 1.f ? deg : 1.f;
    float v = acc / deg + R[(size_t)n * HH + c] + bias[c];
    float ss = v * v;
    ss += __shfl_xor(ss, 1);
    ss += __shfl_xor(ss, 2);
    ss += __shfl_xor(ss, 4);
    ss += __shfl_xor(ss, 8);
    ss += __shfl_xor(ss, 16);
    float nrm = sqrtf(ss);
    nrm = nrm > 1e-12f ? nrm : 1e-12f;
    v = v / nrm;
    v = v > 0.f ? v : 0.f;
    R[(size_t)n * HH + c] = v;
}

__device__ __forceinline__ void pull1f_body(const int* __restrict__ csr,
                                            const int* __restrict__ rs,
                                            const float* __restrict__ S,
                                            const float* __restrict__ R,
                                            const float* __restrict__ b1,
                                            const float* __restrict__ Wp,
                                            const float* __restrict__ bp,
                                            float* __restrict__ out, int vb, float* smem) {
    float* sWpT = smem;
    float* sH   = smem + HH * 33;
    int tid = threadIdx.x;
    {
        float4 a = ((const float4*)Wp)[tid];
        int e0 = tid * 4;
        int o = e0 >> 5, k = e0 & 31;
        sWpT[(k + 0) * 33 + o] = a.x;
        sWpT[(k + 1) * 33 + o] = a.y;
        sWpT[(k + 2) * 33 + o] = a.z;
        sWpT[(k + 3) * 33 + o] = a.w;
    }
    int g = tid >> 5;
    int n = vb * 8 + g;
    int c = tid & 31;
    int s0 = rs[n], s1 = rs[n + 1];
    float acc = 0.f, acc2 = 0.f;
    int j = s0;
    for (; j + 1 < s1; j += 2) {
        int a = csr[j], b = csr[j + 1];
        acc  += S[(size_t)a * HH + c];
        acc2 += S[(size_t)b * HH + c];
    }
    if (j < s1) acc += S[(size_t)csr[j] * HH + c];
    acc += acc2;
    float deg = (float)(s1 - s0);
    deg = deg > 1.f ? deg : 1.f;
    float v = acc / deg + R[(size_t)n * HH + c] + b1[c];
    float ss = v * v;
    ss += __shfl_xor(ss, 1);
    ss += __shfl_xor(ss, 2);
    ss += __shfl_xor(ss, 4);
    ss += __shfl_xor(ss, 8);
    ss += __shfl_xor(ss, 16);
    float nrm = sqrtf(ss);
    nrm = nrm > 1e-12f ? nrm : 1e-12f;
    v = v / nrm;
    v = v > 0.f ? v : 0.f;
    sH[g * 33 + c] = v;
    __syncthreads();
    float a2 = bp[c];
#pragma unroll
    for (int k = 0; k < HH; ++k) a2 += sH[g * 33 + k] * sWpT[k * 33 + c];
    float s2 = a2 * a2;
    s2 += __shfl_xor(s2, 1);
    s2 += __shfl_xor(s2, 2);
    s2 += __shfl_xor(s2, 4);
    s2 += __shfl_xor(s2, 8);
    s2 += __shfl_xor(s2, 16);
    float nrm2 = sqrtf(s2);
    nrm2 = nrm2 > 1e-12f ? nrm2 : 1e-12f;
    out[(size_t)n * HH + c] = a2 / nrm2;
}

// ================= fused same-resource kernels =================

// P1: proj128_U || proj128_I
__global__ __launch_bounds__(1024) void p1_k(const float* __restrict__ xu,
                                             const float* __restrict__ xi,
                                             const float* __restrict__ wl0_ui,
                                             const float* __restrict__ wr0_iu,
                                             const float* __restrict__ wl0_iu,
                                             const float* __restrict__ wr0_ui,
                                             float* __restrict__ Su, float* __restrict__ Ru,
                                             float* __restrict__ Si, float* __restrict__ Ri) {
    __shared__ float smem[2 * FIN * 33 + 32 * 129];
    int b = blockIdx.x;
    if (b < G_PU) proj128_body(xu, wl0_ui, wr0_iu, Su, Ru, NU, b, smem);
    else          proj128_body(xi, wl0_iu, wr0_ui, Si, Ri, NI, b - G_PU, smem);
}

// P2: pull0_I || pull0_U
__global__ void p2_k(const int* __restrict__ csrI, const int* __restrict__ rsI,
                     const float* __restrict__ Su, float* __restrict__ Ri,
                     const float* __restrict__ b0_ui,
                     const int* __restrict__ csrU, const int* __restrict__ rsU,
                     const float* __restrict__ Si, float* __restrict__ Ru,
                     const float* __restrict__ b0_iu) {
    int b = blockIdx.x;
    if (b < G_P0I) pull0_body(csrI, rsI, Su, Ri, b0_ui, b);
    else           pull0_body(csrU, rsU, Si, Ru, b0_iu, b - G_P0I);
}

// P3: proj32(item1) || proj32(user1)
__global__ void p3_k(float* __restrict__ Ri, const float* __restrict__ wl1_iu,
                     const float* __restrict__ wr1_ui, float* __restrict__ Si2,
                     float* __restrict__ Ru, const float* __restrict__ wl1_ui,
                     const float* __restrict__ wr1_iu, float* __restrict__ Su2) {
    __shared__ float smem[2 * HH * 33 + 8 * 33];
    int b = blockIdx.x;
    if (b < G_P0I) proj32_body(Ri, wl1_iu, wr1_ui, Si2, Ri, b, smem);
    else           proj32_body(Ru, wl1_ui, wr1_iu, Su2, Ru, b - G_P0I, smem);
}

// P4: pull1final_U || pull1final_I
__global__ void p4_k(const int* __restrict__ csrU, const int* __restrict__ rsU,
                     const float* __restrict__ Si2, const float* __restrict__ Ru,
                     const float* __restrict__ b1_iu,
                     const float* __restrict__ wp_user, const float* __restrict__ bp_user,
                     const int* __restrict__ csrI, const int* __restrict__ rsI,
                     const float* __restrict__ Su2, const float* __restrict__ Ri,
                     const float* __restrict__ b1_ui,
                     const float* __restrict__ wp_item, const float* __restrict__ bp_item,
                     float* __restrict__ out) {
    __shared__ float smem[HH * 33 + 8 * 33];
    int b = blockIdx.x;
    if (b < G_P0U) {
        pull1f_body(csrU, rsU, Si2, Ru, b1_iu, wp_user, bp_user, out, b, smem);
    } else {
        pull1f_body(csrI, rsI, Su2, Ri, b1_ui, wp_item, bp_item,
                    out + (size_t)NU * HH, b - G_P0U, smem);
    }
}

// ================= host =================

extern "C" void kernel_launch(void* const* d_in, const int* in_sizes, int n_in,
                              void* d_out, int out_size, void* d_ws, size_t ws_size,
                              hipStream_t stream) {
    const float* x_user = (const float*)d_in[0];
    const float* x_item = (const float*)d_in[1];
    const int* eu = (const int*)d_in[2];
    const int* ei = (const int*)d_in[3];
    const float* wl0_ui = (const float*)d_in[4];
    const float* b0_ui  = (const float*)d_in[5];
    const float* wr0_ui = (const float*)d_in[6];
    const float* wl0_iu = (const float*)d_in[7];
    const float* b0_iu  = (const float*)d_in[8];
    const float* wr0_iu = (const float*)d_in[9];
    const float* wl1_ui = (const float*)d_in[10];
    const float* b1_ui  = (const float*)d_in[11];
    const float* wr1_ui = (const float*)d_in[12];
    const float* wl1_iu = (const float*)d_in[13];
    const float* b1_iu  = (const float*)d_in[14];
    const float* wr1_iu = (const float*)d_in[15];
    const float* wp_user = (const float*)d_in[16];
    const float* bp_user = (const float*)d_in[17];
    const float* wp_item = (const float*)d_in[18];
    const float* bp_item = (const float*)d_in[19];
    float* out = (float*)d_out;
    (void)in_sizes; (void)n_in; (void)out_size; (void)ws_size;

    char* base = (char*)d_ws;
    size_t off = 0;
    auto take = [&](size_t bytes) -> size_t {
        size_t o = off;
        off += (bytes + 255) & ~(size_t)255;
        return o;
    };
    size_t o_curU = take((size_t)NU * 4);
    size_t o_curI = take((size_t)NI * 4);
    size_t zero_end = off;
    size_t o_rsU  = take((size_t)(NU + 1) * 4);
    size_t o_rsI  = take((size_t)(NI + 1) * 4);
    size_t o_partU = take(256 * 4);
    size_t o_partI = take(256 * 4);
    size_t o_csrU = take((size_t)NE * 4);
    size_t o_csrI = take((size_t)NE * 4);
    size_t o_Su = take((size_t)NU * HH * 4);     // layer0 user->item msgs; reused as Si2
    size_t o_Si = take((size_t)NI * HH * 4);
    size_t o_Ru = take((size_t)NU * HH * 4);
    size_t o_Ri = take((size_t)NI * HH * 4);
    size_t o_Su2 = take((size_t)NU * HH * 4);

    int* curU = (int*)(base + o_curU);
    int* curI = (int*)(base + o_curI);
    int* rsU  = (int*)(base + o_rsU);
    int* rsI  = (int*)(base + o_rsI);
    int* partU = (int*)(base + o_partU);
    int* partI = (int*)(base + o_partI);
    int* csrU = (int*)(base + o_csrU);
    int* csrI = (int*)(base + o_csrI);
    float* Su = (float*)(base + o_Su);
    float* Si = (float*)(base + o_Si);
    float* Ru = (float*)(base + o_Ru);
    float* Ri = (float*)(base + o_Ri);
    float* Su2 = (float*)(base + o_Su2);
    float* Si2 = Su;   // Su free after P2

    const int nbU = (NU + CHUNK - 1) / CHUNK;   // 98
    const int nbI = (NI + CHUNK - 1) / CHUNK;   // 49

    hipMemsetAsync(base, 0, zero_end, stream);

    // degree counts via LDS-privatized range histograms (atomic-free-ish)
    hist_k<<<G_HU + G_HI, 1024, 0, stream>>>((const int4*)eu, (const int4*)ei, curU, curI);

    // scans
    scanA_k<<<nbU, 256, 0, stream>>>(curU, NU, rsU, partU);
    scanA_k<<<nbI, 256, 0, stream>>>(curI, NI, rsI, partI);
    scanB_k<<<1, 256, 0, stream>>>(partU, nbU, partI, nbI);
    scanC_k<<<(NU + 256) / 256, 256, 0, stream>>>(rsU, partU, NU, curU);
    scanC_k<<<(NI + 256) / 256, 256, 0, stream>>>(rsI, partI, NI, curI);

    // CSR fill, both directions (proven form)
    fill_k<<<G_FILL, 256, 0, stream>>>((const int4*)eu, (const int4*)ei,
                                       curU, curI, csrU, csrI);

    // layer-0 projections
    p1_k<<<G_PU + G_PI, 1024, 0, stream>>>(x_user, x_item, wl0_ui, wr0_iu,
                                           wl0_iu, wr0_ui, Su, Ru, Si, Ri);

    // layer-0 pulls (item1 -> Ri, user1 -> Ru)
    p2_k<<<G_P0I + G_P0U, 256, 0, stream>>>(csrI, rsI, Su, Ri, b0_ui,
                                            csrU, rsU, Si, Ru, b0_iu);

    // layer-1 projections (in place)
    p3_k<<<G_P0I + G_P0U, 256, 0, stream>>>(Ri, wl1_iu, wr1_ui, Si2,
                                            Ru, wl1_ui, wr1_iu, Su2);

    // layer-1 pulls + final projections -> out
    p4_k<<<G_P0U + G_P0I, 256, 0, stream>>>(csrU, rsU, Si2, Ru, b1_iu, wp_user, bp_user,
                                            csrI, rsI, Su2, Ri, b1_ui, wp_item, bp_item,
                                            out);
}

// Round 11
// 344.954 us; speedup vs baseline: 1.3128x; 1.3128x over previous
//
#include <hip/hip_runtime.h>

#define NU 100000
#define NI 50000
#define NE 819200
#define FIN 128
#define HH 32
#define CHUNK 1024

#define G_FILL 800      // NE/4/256
#define G_P0I 6250      // NI/8
#define G_P0U 12500     // NU/8
#define G_P128U 1563    // ceil(NU/64)
#define G_P128I 782     // ceil(NI/64)

// hist: 16384 nodes per range (32KB packed 16-bit LDS), 50 chunks of 16384 edges
#define HRNG 16384
#define HNCH 50
#define HC4  4096       // int4 per chunk
#define G_HU 350        // 7 ranges * 50 chunks
#define G_HI 200        // 4 ranges * 50 chunks

// ================= histogram degree count =================
__global__ __launch_bounds__(1024) void hist_k(const int4* __restrict__ eu4,
                                               const int4* __restrict__ ei4,
                                               int* __restrict__ curU,
                                               int* __restrict__ curI) {
    __shared__ unsigned sh[HRNG / 2];
    int tid = threadIdx.x;
    int b = blockIdx.x;
    const int4* E;
    int* cur;
    int lo, N, chunk;
    if (b < G_HU) {
        E = eu4; cur = curU; N = NU;
        lo = (b / HNCH) * HRNG; chunk = b % HNCH;
    } else {
        int bb = b - G_HU;
        E = ei4; cur = curI; N = NI;
        lo = (bb / HNCH) * HRNG; chunk = bb % HNCH;
    }
    for (int i = tid; i < HRNG / 2; i += 1024) sh[i] = 0u;
    __syncthreads();
    int base = chunk * HC4;
#pragma unroll
    for (int it = 0; it < HC4 / 1024; ++it) {
        int4 v = E[base + it * 1024 + tid];
        int d;
        d = v.x - lo; if ((unsigned)d < (unsigned)HRNG) atomicAdd(&sh[d >> 1], (d & 1) ? 65536u : 1u);
        d = v.y - lo; if ((unsigned)d < (unsigned)HRNG) atomicAdd(&sh[d >> 1], (d & 1) ? 65536u : 1u);
        d = v.z - lo; if ((unsigned)d < (unsigned)HRNG) atomicAdd(&sh[d >> 1], (d & 1) ? 65536u : 1u);
        d = v.w - lo; if ((unsigned)d < (unsigned)HRNG) atomicAdd(&sh[d >> 1], (d & 1) ? 65536u : 1u);
    }
    __syncthreads();
    for (int i = tid; i < HRNG / 2; i += 1024) {
        unsigned w = sh[i];
        if (w) {
            int n0 = lo + 2 * i;
            unsigned c0 = w & 0xFFFFu, c1 = w >> 16;
            if (c0 && n0 < N) atomicAdd(cur + n0, (int)c0);
            if (c1 && n0 + 1 < N) atomicAdd(cur + n0 + 1, (int)c1);
        }
    }
}

// ================= scans =================
__global__ void scanA_k(const int* __restrict__ src, int n,
                        int* __restrict__ dst, int* __restrict__ part) {
    __shared__ int ts[256];
    int t = threadIdx.x, b = blockIdx.x;
    int base = b * CHUNK + t * 4;
    int v0 = 0, v1 = 0, v2 = 0, v3 = 0;
    if (base + 0 < n) v0 = src[base + 0];
    if (base + 1 < n) v1 = src[base + 1];
    if (base + 2 < n) v2 = src[base + 2];
    if (base + 3 < n) v3 = src[base + 3];
    int s = v0 + v1 + v2 + v3;
    ts[t] = s;
    __syncthreads();
    int incl = s;
    for (int off = 1; off < 256; off <<= 1) {
        int y = (t >= off) ? ts[t - off] : 0;
        __syncthreads();
        incl += y;
        ts[t] = incl;
        __syncthreads();
    }
    if (t == 255) part[b] = incl;
    int r = incl - s;
    if (base + 0 < n) dst[base + 0] = r; r += v0;
    if (base + 1 < n) dst[base + 1] = r; r += v1;
    if (base + 2 < n) dst[base + 2] = r; r += v2;
    if (base + 3 < n) dst[base + 3] = r;
}

__global__ void scanB_k(int* __restrict__ pU, int nU, int* __restrict__ pI, int nI) {
    __shared__ int ts[256];
    int t = threadIdx.x;
    for (int a = 0; a < 2; ++a) {
        int* p = a ? pI : pU;
        int nb = a ? nI : nU;
        int v = (t < nb) ? p[t] : 0;
        ts[t] = v;
        __syncthreads();
        int incl = v;
        for (int off = 1; off < 256; off <<= 1) {
            int y = (t >= off) ? ts[t - off] : 0;
            __syncthreads();
            incl += y;
            ts[t] = incl;
            __syncthreads();
        }
        if (t < nb) p[t] = incl - v;
        __syncthreads();
    }
}

__global__ void scanC_k(int* __restrict__ rs, const int* __restrict__ part, int n,
                        int* __restrict__ cur) {
    int i = blockIdx.x * 256 + threadIdx.x;
    if (i < n) {
        int v = rs[i] + part[i >> 10];
        rs[i] = v;
        cur[i] = v;
    } else if (i == n) {
        rs[n] = NE;
    }
}

// ================= CSR fill =================
__global__ void fill_k(const int4* __restrict__ eu4, const int4* __restrict__ ei4,
                       int* __restrict__ curU, int* __restrict__ curI,
                       int* __restrict__ csrU, int* __restrict__ csrI) {
    int t = blockIdx.x * 256 + threadIdx.x;
    int4 u = eu4[t];
    int4 i = ei4[t];
    int a0 = atomicAdd(curI + i.x, 1);
    int a1 = atomicAdd(curI + i.y, 1);
    int a2 = atomicAdd(curI + i.z, 1);
    int a3 = atomicAdd(curI + i.w, 1);
    int b0 = atomicAdd(curU + u.x, 1);
    int b1 = atomicAdd(curU + u.y, 1);
    int b2 = atomicAdd(curU + u.z, 1);
    int b3 = atomicAdd(curU + u.w, 1);
    csrI[a0] = u.x;
    csrI[a1] = u.y;
    csrI[a2] = u.z;
    csrI[a3] = u.w;
    csrU[b0] = i.x;
    csrU[b1] = i.y;
    csrU[b2] = i.z;
    csrU[b3] = i.w;
}

// ================= proj128: 64 nodes x 64 cols, 4x4 register tile =================
__device__ __forceinline__ void proj128_body(const float* __restrict__ X,
                                             const float* __restrict__ Wl,
                                             const float* __restrict__ Wr,
                                             float* __restrict__ S, float* __restrict__ R,
                                             int N, int vb, float* smem) {
    float* sW = smem;                 // [128][68], col-major-in-col: sW[k*68+col]
    float* sX = smem + 128 * 68;      // [64][132]
    int tid = threadIdx.x;
#pragma unroll
    for (int it = 0; it < 8; ++it) {           // 2048 float4 = 64 cols x 128 k
        int idx = it * 256 + tid;
        int col = idx & 63, k = (idx >> 6) * 4;
        const float* src = (col < 32) ? (Wl + col * FIN + k) : (Wr + (col - 32) * FIN + k);
        float4 w = *(const float4*)src;
        sW[(k + 0) * 68 + col] = w.x;
        sW[(k + 1) * 68 + col] = w.y;
        sW[(k + 2) * 68 + col] = w.z;
        sW[(k + 3) * 68 + col] = w.w;
    }
    int n0 = vb * 64;
#pragma unroll
    for (int it = 0; it < 8; ++it) {           // 2048 float4 = 64 nodes x 128 k
        int idx = it * 256 + tid;
        int n = idx >> 5, k4 = (idx & 31) * 4;
        if (n0 + n < N) {
            float4 v = *(const float4*)(X + (size_t)(n0 + n) * FIN + k4);
            *(float4*)&sX[n * 132 + k4] = v;
        }
    }
    __syncthreads();
    int ct = tid & 15, nt = tid >> 4;
    int c0 = ct * 4;
    int nb = nt * 4;
    float acc[4][4];
#pragma unroll
    for (int j = 0; j < 4; ++j)
#pragma unroll
        for (int i = 0; i < 4; ++i) acc[j][i] = 0.f;
#pragma unroll 4
    for (int k = 0; k < FIN; ++k) {
        float4 w = *(const float4*)&sW[k * 68 + c0];
        float x0 = sX[(nb + 0) * 132 + k];
        float x1 = sX[(nb + 1) * 132 + k];
        float x2 = sX[(nb + 2) * 132 + k];
        float x3 = sX[(nb + 3) * 132 + k];
        acc[0][0] += x0 * w.x; acc[0][1] += x0 * w.y; acc[0][2] += x0 * w.z; acc[0][3] += x0 * w.w;
        acc[1][0] += x1 * w.x; acc[1][1] += x1 * w.y; acc[1][2] += x1 * w.z; acc[1][3] += x1 * w.w;
        acc[2][0] += x2 * w.x; acc[2][1] += x2 * w.y; acc[2][2] += x2 * w.z; acc[2][3] += x2 * w.w;
        acc[3][0] += x3 * w.x; acc[3][1] += x3 * w.y; acc[3][2] += x3 * w.z; acc[3][3] += x3 * w.w;
    }
#pragma unroll
    for (int j = 0; j < 4; ++j) {
        int node = n0 + nb + j;
        if (node < N) {
            float4 o;
            o.x = acc[j][0]; o.y = acc[j][1]; o.z = acc[j][2]; o.w = acc[j][3];
            if (c0 < 32) *(float4*)(S + (size_t)node * HH + c0) = o;
            else         *(float4*)(R + (size_t)node * HH + (c0 - 32)) = o;
        }
    }
}

__global__ __launch_bounds__(256) void p1_k(const float* __restrict__ xu,
                                            const float* __restrict__ xi,
                                            const float* __restrict__ wl0_ui,
                                            const float* __restrict__ wr0_iu,
                                            const float* __restrict__ wl0_iu,
                                            const float* __restrict__ wr0_ui,
                                            float* __restrict__ Su, float* __restrict__ Ru,
                                            float* __restrict__ Si, float* __restrict__ Ri) {
    __shared__ float smem[128 * 68 + 64 * 132];
    int b = blockIdx.x;
    if (b < G_P128U) proj128_body(xu, wl0_ui, wr0_iu, Su, Ru, NU, b, smem);
    else             proj128_body(xi, wl0_iu, wr0_ui, Si, Ri, NI, b - G_P128U, smem);
}

// ================= fused pull0 + proj32 =================
// pull0: h1 = relu(l2norm(mean_gather(S) + R + b)); then S2 = h1@Wl^T, R = h1@Wr^T
__global__ void p23_k(const int* __restrict__ csrI, const int* __restrict__ rsI,
                      const float* __restrict__ Su, float* __restrict__ Ri,
                      const float* __restrict__ b0_ui,
                      const float* __restrict__ wl1_iu, const float* __restrict__ wr1_ui,
                      float* __restrict__ Si2,
                      const int* __restrict__ csrU, const int* __restrict__ rsU,
                      const float* __restrict__ Si, float* __restrict__ Ru,
                      const float* __restrict__ b0_iu,
                      const float* __restrict__ wl1_ui, const float* __restrict__ wr1_iu,
                      float* __restrict__ Su2) {
    __shared__ float sWl[HH * 36];
    __shared__ float sWr[HH * 36];
    __shared__ float sH[8][36];
    int b = blockIdx.x;
    const int *csr, *rs;
    const float *S, *bias, *Wl, *Wr;
    float *Rb, *S2;
    int vb;
    if (b < G_P0I) {
        csr = csrI; rs = rsI; S = Su; Rb = Ri; bias = b0_ui;
        Wl = wl1_iu; Wr = wr1_ui; S2 = Si2; vb = b;
    } else {
        csr = csrU; rs = rsU; S = Si; Rb = Ru; bias = b0_iu;
        Wl = wl1_ui; Wr = wr1_iu; S2 = Su2; vb = b - G_P0I;
    }
    int tid = threadIdx.x;
    {
        float4 a = ((const float4*)Wl)[tid];   // 256 float4 = 1024 = 32x32
        float4 w = ((const float4*)Wr)[tid];
        int e0 = tid * 4;
        int o = e0 >> 5, k = e0 & 31;
        sWl[(k + 0) * 36 + o] = a.x;
        sWl[(k + 1) * 36 + o] = a.y;
        sWl[(k + 2) * 36 + o] = a.z;
        sWl[(k + 3) * 36 + o] = a.w;
        sWr[(k + 0) * 36 + o] = w.x;
        sWr[(k + 1) * 36 + o] = w.y;
        sWr[(k + 2) * 36 + o] = w.z;
        sWr[(k + 3) * 36 + o] = w.w;
    }
    int g = tid >> 5, c = tid & 31;
    int n = vb * 8 + g;
    int s0 = rs[n], s1 = rs[n + 1];
    float a0 = 0.f, a1 = 0.f, a2 = 0.f, a3 = 0.f;
    int j = s0;
    for (; j + 3 < s1; j += 4) {
        int i0 = csr[j], i1 = csr[j + 1], i2 = csr[j + 2], i3 = csr[j + 3];
        a0 += S[(size_t)i0 * HH + c];
        a1 += S[(size_t)i1 * HH + c];
        a2 += S[(size_t)i2 * HH + c];
        a3 += S[(size_t)i3 * HH + c];
    }
    for (; j < s1; ++j) a0 += S[(size_t)csr[j] * HH + c];
    float acc = (a0 + a1) + (a2 + a3);
    float deg = (float)(s1 - s0);
    deg = deg > 1.f ? deg : 1.f;
    float v = acc / deg + Rb[(size_t)n * HH + c] + bias[c];
    float ss = v * v;
    ss += __shfl_xor(ss, 1);
    ss += __shfl_xor(ss, 2);
    ss += __shfl_xor(ss, 4);
    ss += __shfl_xor(ss, 8);
    ss += __shfl_xor(ss, 16);
    float nrm = sqrtf(ss);
    nrm = nrm > 1e-12f ? nrm : 1e-12f;
    v = v / nrm;
    v = v > 0.f ? v : 0.f;
    sH[g][c] = v;
    __syncthreads();
    float aL = 0.f, aR = 0.f;
#pragma unroll
    for (int k = 0; k < HH; ++k) {
        float x = sH[g][k];
        aL += x * sWl[k * 36 + c];
        aR += x * sWr[k * 36 + c];
    }
    S2[(size_t)n * HH + c] = aL;
    Rb[(size_t)n * HH + c] = aR;
}

// ================= pull1 + final =================
__device__ __forceinline__ void pull1f_body(const int* __restrict__ csr,
                                            const int* __restrict__ rs,
                                            const float* __restrict__ S,
                                            const float* __restrict__ R,
                                            const float* __restrict__ b1,
                                            const float* __restrict__ Wp,
                                            const float* __restrict__ bp,
                                            float* __restrict__ out, int vb, float* smem) {
    float* sWpT = smem;              // [32][36]
    float* sH   = smem + HH * 36;    // [8][36]
    int tid = threadIdx.x;
    {
        float4 a = ((const float4*)Wp)[tid];
        int e0 = tid * 4;
        int o = e0 >> 5, k = e0 & 31;
        sWpT[(k + 0) * 36 + o] = a.x;
        sWpT[(k + 1) * 36 + o] = a.y;
        sWpT[(k + 2) * 36 + o] = a.z;
        sWpT[(k + 3) * 36 + o] = a.w;
    }
    int g = tid >> 5;
    int n = vb * 8 + g;
    int c = tid & 31;
    int s0 = rs[n], s1 = rs[n + 1];
    float a0 = 0.f, a1 = 0.f, a2 = 0.f, a3 = 0.f;
    int j = s0;
    for (; j + 3 < s1; j += 4) {
        int i0 = csr[j], i1 = csr[j + 1], i2 = csr[j + 2], i3 = csr[j + 3];
        a0 += S[(size_t)i0 * HH + c];
        a1 += S[(size_t)i1 * HH + c];
        a2 += S[(size_t)i2 * HH + c];
        a3 += S[(size_t)i3 * HH + c];
    }
    for (; j < s1; ++j) a0 += S[(size_t)csr[j] * HH + c];
    float acc = (a0 + a1) + (a2 + a3);
    float deg = (float)(s1 - s0);
    deg = deg > 1.f ? deg : 1.f;
    float v = acc / deg + R[(size_t)n * HH + c] + b1[c];
    float ss = v * v;
    ss += __shfl_xor(ss, 1);
    ss += __shfl_xor(ss, 2);
    ss += __shfl_xor(ss, 4);
    ss += __shfl_xor(ss, 8);
    ss += __shfl_xor(ss, 16);
    float nrm = sqrtf(ss);
    nrm = nrm > 1e-12f ? nrm : 1e-12f;
    v = v / nrm;
    v = v > 0.f ? v : 0.f;
    sH[g * 36 + c] = v;
    __syncthreads();
    float a2f = bp[c];
#pragma unroll
    for (int k = 0; k < HH; ++k) a2f += sH[g * 36 + k] * sWpT[k * 36 + c];
    float s2 = a2f * a2f;
    s2 += __shfl_xor(s2, 1);
    s2 += __shfl_xor(s2, 2);
    s2 += __shfl_xor(s2, 4);
    s2 += __shfl_xor(s2, 8);
    s2 += __shfl_xor(s2, 16);
    float nrm2 = sqrtf(s2);
    nrm2 = nrm2 > 1e-12f ? nrm2 : 1e-12f;
    out[(size_t)n * HH + c] = a2f / nrm2;
}

__global__ void p4_k(const int* __restrict__ csrU, const int* __restrict__ rsU,
                     const float* __restrict__ Si2, const float* __restrict__ Ru,
                     const float* __restrict__ b1_iu,
                     const float* __restrict__ wp_user, const float* __restrict__ bp_user,
                     const int* __restrict__ csrI, const int* __restrict__ rsI,
                     const float* __restrict__ Su2, const float* __restrict__ Ri,
                     const float* __restrict__ b1_ui,
                     const float* __restrict__ wp_item, const float* __restrict__ bp_item,
                     float* __restrict__ out) {
    __shared__ float smem[HH * 36 + 8 * 36];
    int b = blockIdx.x;
    if (b < G_P0U) {
        pull1f_body(csrU, rsU, Si2, Ru, b1_iu, wp_user, bp_user, out, b, smem);
    } else {
        pull1f_body(csrI, rsI, Su2, Ri, b1_ui, wp_item, bp_item,
                    out + (size_t)NU * HH, b - G_P0U, smem);
    }
}

// ================= host =================

extern "C" void kernel_launch(void* const* d_in, const int* in_sizes, int n_in,
                              void* d_out, int out_size, void* d_ws, size_t ws_size,
                              hipStream_t stream) {
    const float* x_user = (const float*)d_in[0];
    const float* x_item = (const float*)d_in[1];
    const int* eu = (const int*)d_in[2];
    const int* ei = (const int*)d_in[3];
    const float* wl0_ui = (const float*)d_in[4];
    const float* b0_ui  = (const float*)d_in[5];
    const float* wr0_ui = (const float*)d_in[6];
    const float* wl0_iu = (const float*)d_in[7];
    const float* b0_iu  = (const float*)d_in[8];
    const float* wr0_iu = (const float*)d_in[9];
    const float* wl1_ui = (const float*)d_in[10];
    const float* b1_ui  = (const float*)d_in[11];
    const float* wr1_ui = (const float*)d_in[12];
    const float* wl1_iu = (const float*)d_in[13];
    const float* b1_iu  = (const float*)d_in[14];
    const float* wr1_iu = (const float*)d_in[15];
    const float* wp_user = (const float*)d_in[16];
    const float* bp_user = (const float*)d_in[17];
    const float* wp_item = (const float*)d_in[18];
    const float* bp_item = (const float*)d_in[19];
    float* out = (float*)d_out;
    (void)in_sizes; (void)n_in; (void)out_size; (void)ws_size;

    char* base = (char*)d_ws;
    size_t off = 0;
    auto take = [&](size_t bytes) -> size_t {
        size_t o = off;
        off += (bytes + 255) & ~(size_t)255;
        return o;
    };
    size_t o_curU = take((size_t)NU * 4);
    size_t o_curI = take((size_t)NI * 4);
    size_t zero_end = off;
    size_t o_rsU  = take((size_t)(NU + 1) * 4);
    size_t o_rsI  = take((size_t)(NI + 1) * 4);
    size_t o_partU = take(256 * 4);
    size_t o_partI = take(256 * 4);
    size_t o_csrU = take((size_t)NE * 4);
    size_t o_csrI = take((size_t)NE * 4);
    size_t o_Su = take((size_t)NU * HH * 4);
    size_t o_Si = take((size_t)NI * HH * 4);
    size_t o_Ru = take((size_t)NU * HH * 4);
    size_t o_Ri = take((size_t)NI * HH * 4);
    size_t o_Su2 = take((size_t)NU * HH * 4);
    size_t o_Si2 = take((size_t)NI * HH * 4);

    int* curU = (int*)(base + o_curU);
    int* curI = (int*)(base + o_curI);
    int* rsU  = (int*)(base + o_rsU);
    int* rsI  = (int*)(base + o_rsI);
    int* partU = (int*)(base + o_partU);
    int* partI = (int*)(base + o_partI);
    int* csrU = (int*)(base + o_csrU);
    int* csrI = (int*)(base + o_csrI);
    float* Su = (float*)(base + o_Su);
    float* Si = (float*)(base + o_Si);
    float* Ru = (float*)(base + o_Ru);
    float* Ri = (float*)(base + o_Ri);
    float* Su2 = (float*)(base + o_Su2);
    float* Si2 = (float*)(base + o_Si2);

    const int nbU = (NU + CHUNK - 1) / CHUNK;   // 98
    const int nbI = (NI + CHUNK - 1) / CHUNK;   // 49

    hipMemsetAsync(base, 0, zero_end, stream);

    // degree counts via LDS range histograms
    hist_k<<<G_HU + G_HI, 1024, 0, stream>>>((const int4*)eu, (const int4*)ei, curU, curI);

    // scans
    scanA_k<<<nbU, 256, 0, stream>>>(curU, NU, rsU, partU);
    scanA_k<<<nbI, 256, 0, stream>>>(curI, NI, rsI, partI);
    scanB_k<<<1, 256, 0, stream>>>(partU, nbU, partI, nbI);
    scanC_k<<<(NU + 256) / 256, 256, 0, stream>>>(rsU, partU, NU, curU);
    scanC_k<<<(NI + 256) / 256, 256, 0, stream>>>(rsI, partI, NI, curI);

    // CSR fill
    fill_k<<<G_FILL, 256, 0, stream>>>((const int4*)eu, (const int4*)ei,
                                       curU, curI, csrU, csrI);

    // layer-0 projections (register-tiled)
    p1_k<<<G_P128U + G_P128I, 256, 0, stream>>>(x_user, x_item, wl0_ui, wr0_iu,
                                                wl0_iu, wr0_ui, Su, Ru, Si, Ri);

    // layer-0 pulls fused with layer-1 projections
    p23_k<<<G_P0I + G_P0U, 256, 0, stream>>>(csrI, rsI, Su, Ri, b0_ui, wl1_iu, wr1_ui, Si2,
                                             csrU, rsU, Si, Ru, b0_iu, wl1_ui, wr1_iu, Su2);

    // layer-1 pulls + final projections -> out
    p4_k<<<G_P0U + G_P0I, 256, 0, stream>>>(csrU, rsU, Si2, Ru, b1_iu, wp_user, bp_user,
                                            csrI, rsI, Su2, Ri, b1_ui, wp_item, bp_item,
                                            out);
}

// Round 12
// 247.948 us; speedup vs baseline: 1.8265x; 1.3912x over previous
//
#include <hip/hip_runtime.h>

#define NU 100000
#define NI 50000
#define NE 819200
#define FIN 128
#define HH 32

#define NCH 200         // edge chunks of 4096
#define NBU 98          // user buckets of 1024 nodes
#define NBI 49          // item buckets of 1024 nodes

#define G_P0I 6250      // NI/8
#define G_P0U 12500     // NU/8
#define G_P128U 1563    // ceil(NU/64)
#define G_P128I 782     // ceil(NI/64)

// ================= radix CSR build =================

// pass 1: per-(chunk,dir) bucket histogram
__global__ void cnt1_k(const int4* __restrict__ eu4, const int4* __restrict__ ei4,
                       int* __restrict__ cntU, int* __restrict__ cntI) {
    __shared__ unsigned cnt[128];
    int b = blockIdx.x;
    int c, NB;
    const int4* D;
    int* M;
    if (b < NCH) { c = b; D = eu4; M = cntU; NB = NBU; }
    else         { c = b - NCH; D = ei4; M = cntI; NB = NBI; }
    int tid = threadIdx.x;
    if (tid < 128) cnt[tid] = 0u;
    __syncthreads();
    int base = c * 1024;
#pragma unroll
    for (int it = 0; it < 4; ++it) {
        int4 v = D[base + it * 256 + tid];
        atomicAdd(&cnt[v.x >> 10], 1u);
        atomicAdd(&cnt[v.y >> 10], 1u);
        atomicAdd(&cnt[v.z >> 10], 1u);
        atomicAdd(&cnt[v.w >> 10], 1u);
    }
    __syncthreads();
    for (int i = tid; i < NB; i += 256) M[i * NCH + c] = (int)cnt[i];
}

// pass 2: exclusive scan of both matrices, bucket-major (single block)
__global__ __launch_bounds__(1024) void scan2_k(int* __restrict__ aU, int nU,
                                                int* __restrict__ aI, int nI) {
    __shared__ int ts[1024];
    int t = threadIdx.x;
    for (int pass = 0; pass < 2; ++pass) {
        int* a = pass ? aI : aU;
        int n  = pass ? nI : nU;
        int nper = (n + 1023) / 1024;
        int beg = t * nper;
        int end = beg + nper; if (end > n) end = n;
        int s = 0;
        for (int i = beg; i < end; ++i) s += a[i];
        ts[t] = s;
        __syncthreads();
        int incl = s;
        for (int off = 1; off < 1024; off <<= 1) {
            int y = (t >= off) ? ts[t - off] : 0;
            __syncthreads();
            incl += y;
            ts[t] = incl;
            __syncthreads();
        }
        int run = incl - s;
        for (int i = beg; i < end; ++i) { int v = a[i]; a[i] = run; run += v; }
        __syncthreads();
    }
}

// pass 3: partition edges into bucket-ordered (dst,payload) pairs
__global__ void part_k(const int4* __restrict__ eu4, const int4* __restrict__ ei4,
                       const int* __restrict__ cntU, const int* __restrict__ cntI,
                       int2* __restrict__ partU, int2* __restrict__ partI) {
    __shared__ unsigned cur[128];
    int b = blockIdx.x;
    int c, NB;
    const int4 *D, *P;
    const int* M;
    int2* out;
    if (b < NCH) { c = b; D = eu4; P = ei4; M = cntU; out = partU; NB = NBU; }
    else         { c = b - NCH; D = ei4; P = eu4; M = cntI; out = partI; NB = NBI; }
    int tid = threadIdx.x;
    for (int i = tid; i < NB; i += 256) cur[i] = (unsigned)M[i * NCH + c];
    __syncthreads();
    int base = c * 1024;
#pragma unroll
    for (int it = 0; it < 4; ++it) {
        int4 d = D[base + it * 256 + tid];
        int4 p = P[base + it * 256 + tid];
        unsigned s;
        s = atomicAdd(&cur[d.x >> 10], 1u); out[s] = make_int2(d.x, p.x);
        s = atomicAdd(&cur[d.y >> 10], 1u); out[s] = make_int2(d.y, p.y);
        s = atomicAdd(&cur[d.z >> 10], 1u); out[s] = make_int2(d.z, p.z);
        s = atomicAdd(&cur[d.w >> 10], 1u); out[s] = make_int2(d.w, p.w);
    }
}

// pass 4: per-bucket CSR build (rs + csr) entirely from LDS offsets
__global__ __launch_bounds__(1024) void build_k(const int2* __restrict__ partU,
                                                const int2* __restrict__ partI,
                                                const int* __restrict__ cntU,
                                                const int* __restrict__ cntI,
                                                int* __restrict__ rsU, int* __restrict__ rsI,
                                                int* __restrict__ csrU, int* __restrict__ csrI) {
    __shared__ unsigned dcnt[1024];
    __shared__ unsigned sc[1024];
    int b = blockIdx.x;
    const int2* part;
    const int* M;
    int *rs, *csr;
    int bi, N, NB;
    if (b < NBU) { bi = b; part = partU; M = cntU; rs = rsU; csr = csrU; N = NU; NB = NBU; }
    else         { bi = b - NBU; part = partI; M = cntI; rs = rsI; csr = csrI; N = NI; NB = NBI; }
    int lo = bi * 1024;
    int bktbase = M[bi * NCH];
    int bktend = (bi + 1 < NB) ? M[(bi + 1) * NCH] : NE;
    int t = threadIdx.x;
    dcnt[t] = 0u;
    __syncthreads();
    for (int j = bktbase + t; j < bktend; j += 1024) {
        int2 p = part[j];
        atomicAdd(&dcnt[p.x - lo], 1u);
    }
    __syncthreads();
    unsigned cme = dcnt[t];
    sc[t] = cme;
    __syncthreads();
    unsigned incl = cme;
    for (int off = 1; off < 1024; off <<= 1) {
        unsigned y = (t >= off) ? sc[t - off] : 0u;
        __syncthreads();
        incl += y;
        sc[t] = incl;
        __syncthreads();
    }
    unsigned excl = incl - cme;
    if (lo + t < N) rs[lo + t] = bktbase + (int)excl;
    if (bi == NB - 1 && t == 0) rs[N] = NE;
    __syncthreads();
    dcnt[t] = excl;
    __syncthreads();
    for (int j = bktbase + t; j < bktend; j += 1024) {
        int2 p = part[j];
        unsigned s = atomicAdd(&dcnt[p.x - lo], 1u);
        csr[bktbase + (int)s] = p.y;
    }
}

// ================= proj128: 64 nodes x 64 cols, 4x4 register tile =================
__device__ __forceinline__ void proj128_body(const float* __restrict__ X,
                                             const float* __restrict__ Wl,
                                             const float* __restrict__ Wr,
                                             float* __restrict__ S, float* __restrict__ R,
                                             int N, int vb, float* smem) {
    float* sW = smem;                 // [128][68]
    float* sX = smem + 128 * 68;      // [64][132]
    int tid = threadIdx.x;
#pragma unroll
    for (int it = 0; it < 8; ++it) {
        int idx = it * 256 + tid;
        int col = idx & 63, k = (idx >> 6) * 4;
        const float* src = (col < 32) ? (Wl + col * FIN + k) : (Wr + (col - 32) * FIN + k);
        float4 w = *(const float4*)src;
        sW[(k + 0) * 68 + col] = w.x;
        sW[(k + 1) * 68 + col] = w.y;
        sW[(k + 2) * 68 + col] = w.z;
        sW[(k + 3) * 68 + col] = w.w;
    }
    int n0 = vb * 64;
#pragma unroll
    for (int it = 0; it < 8; ++it) {
        int idx = it * 256 + tid;
        int n = idx >> 5, k4 = (idx & 31) * 4;
        if (n0 + n < N) {
            float4 v = *(const float4*)(X + (size_t)(n0 + n) * FIN + k4);
            *(float4*)&sX[n * 132 + k4] = v;
        }
    }
    __syncthreads();
    int ct = tid & 15, nt = tid >> 4;
    int c0 = ct * 4;
    int nb = nt * 4;
    float acc[4][4];
#pragma unroll
    for (int j = 0; j < 4; ++j)
#pragma unroll
        for (int i = 0; i < 4; ++i) acc[j][i] = 0.f;
#pragma unroll 4
    for (int k = 0; k < FIN; ++k) {
        float4 w = *(const float4*)&sW[k * 68 + c0];
        float x0 = sX[(nb + 0) * 132 + k];
        float x1 = sX[(nb + 1) * 132 + k];
        float x2 = sX[(nb + 2) * 132 + k];
        float x3 = sX[(nb + 3) * 132 + k];
        acc[0][0] += x0 * w.x; acc[0][1] += x0 * w.y; acc[0][2] += x0 * w.z; acc[0][3] += x0 * w.w;
        acc[1][0] += x1 * w.x; acc[1][1] += x1 * w.y; acc[1][2] += x1 * w.z; acc[1][3] += x1 * w.w;
        acc[2][0] += x2 * w.x; acc[2][1] += x2 * w.y; acc[2][2] += x2 * w.z; acc[2][3] += x2 * w.w;
        acc[3][0] += x3 * w.x; acc[3][1] += x3 * w.y; acc[3][2] += x3 * w.z; acc[3][3] += x3 * w.w;
    }
#pragma unroll
    for (int j = 0; j < 4; ++j) {
        int node = n0 + nb + j;
        if (node < N) {
            float4 o;
            o.x = acc[j][0]; o.y = acc[j][1]; o.z = acc[j][2]; o.w = acc[j][3];
            if (c0 < 32) *(float4*)(S + (size_t)node * HH + c0) = o;
            else         *(float4*)(R + (size_t)node * HH + (c0 - 32)) = o;
        }
    }
}

__global__ __launch_bounds__(256) void p1_k(const float* __restrict__ xu,
                                            const float* __restrict__ xi,
                                            const float* __restrict__ wl0_ui,
                                            const float* __restrict__ wr0_iu,
                                            const float* __restrict__ wl0_iu,
                                            const float* __restrict__ wr0_ui,
                                            float* __restrict__ Su, float* __restrict__ Ru,
                                            float* __restrict__ Si, float* __restrict__ Ri) {
    __shared__ float smem[128 * 68 + 64 * 132];
    int b = blockIdx.x;
    if (b < G_P128U) proj128_body(xu, wl0_ui, wr0_iu, Su, Ru, NU, b, smem);
    else             proj128_body(xi, wl0_iu, wr0_ui, Si, Ri, NI, b - G_P128U, smem);
}

// ================= fused pull0 + proj32 =================
__global__ void p23_k(const int* __restrict__ csrI, const int* __restrict__ rsI,
                      const float* __restrict__ Su, float* __restrict__ Ri,
                      const float* __restrict__ b0_ui,
                      const float* __restrict__ wl1_iu, const float* __restrict__ wr1_ui,
                      float* __restrict__ Si2,
                      const int* __restrict__ csrU, const int* __restrict__ rsU,
                      const float* __restrict__ Si, float* __restrict__ Ru,
                      const float* __restrict__ b0_iu,
                      const float* __restrict__ wl1_ui, const float* __restrict__ wr1_iu,
                      float* __restrict__ Su2) {
    __shared__ float sWl[HH * 36];
    __shared__ float sWr[HH * 36];
    __shared__ float sH[8][36];
    int b = blockIdx.x;
    const int *csr, *rs;
    const float *S, *bias, *Wl, *Wr;
    float *Rb, *S2;
    int vb;
    if (b < G_P0I) {
        csr = csrI; rs = rsI; S = Su; Rb = Ri; bias = b0_ui;
        Wl = wl1_iu; Wr = wr1_ui; S2 = Si2; vb = b;
    } else {
        csr = csrU; rs = rsU; S = Si; Rb = Ru; bias = b0_iu;
        Wl = wl1_ui; Wr = wr1_iu; S2 = Su2; vb = b - G_P0I;
    }
    int tid = threadIdx.x;
    {
        float4 a = ((const float4*)Wl)[tid];
        float4 w = ((const float4*)Wr)[tid];
        int e0 = tid * 4;
        int o = e0 >> 5, k = e0 & 31;
        sWl[(k + 0) * 36 + o] = a.x;
        sWl[(k + 1) * 36 + o] = a.y;
        sWl[(k + 2) * 36 + o] = a.z;
        sWl[(k + 3) * 36 + o] = a.w;
        sWr[(k + 0) * 36 + o] = w.x;
        sWr[(k + 1) * 36 + o] = w.y;
        sWr[(k + 2) * 36 + o] = w.z;
        sWr[(k + 3) * 36 + o] = w.w;
    }
    int g = tid >> 5, c = tid & 31;
    int n = vb * 8 + g;
    int s0 = rs[n], s1 = rs[n + 1];
    float a0 = 0.f, a1 = 0.f, a2 = 0.f, a3 = 0.f;
    int j = s0;
    for (; j + 3 < s1; j += 4) {
        int i0 = csr[j], i1 = csr[j + 1], i2 = csr[j + 2], i3 = csr[j + 3];
        a0 += S[(size_t)i0 * HH + c];
        a1 += S[(size_t)i1 * HH + c];
        a2 += S[(size_t)i2 * HH + c];
        a3 += S[(size_t)i3 * HH + c];
    }
    for (; j < s1; ++j) a0 += S[(size_t)csr[j] * HH + c];
    float acc = (a0 + a1) + (a2 + a3);
    float deg = (float)(s1 - s0);
    deg = deg > 1.f ? deg : 1.f;
    float v = acc / deg + Rb[(size_t)n * HH + c] + bias[c];
    float ss = v * v;
    ss += __shfl_xor(ss, 1);
    ss += __shfl_xor(ss, 2);
    ss += __shfl_xor(ss, 4);
    ss += __shfl_xor(ss, 8);
    ss += __shfl_xor(ss, 16);
    float nrm = sqrtf(ss);
    nrm = nrm > 1e-12f ? nrm : 1e-12f;
    v = v / nrm;
    v = v > 0.f ? v : 0.f;
    sH[g][c] = v;
    __syncthreads();
    float aL = 0.f, aR = 0.f;
#pragma unroll
    for (int k = 0; k < HH; ++k) {
        float x = sH[g][k];
        aL += x * sWl[k * 36 + c];
        aR += x * sWr[k * 36 + c];
    }
    S2[(size_t)n * HH + c] = aL;
    Rb[(size_t)n * HH + c] = aR;
}

// ================= pull1 + final =================
__device__ __forceinline__ void pull1f_body(const int* __restrict__ csr,
                                            const int* __restrict__ rs,
                                            const float* __restrict__ S,
                                            const float* __restrict__ R,
                                            const float* __restrict__ b1,
                                            const float* __restrict__ Wp,
                                            const float* __restrict__ bp,
                                            float* __restrict__ out, int vb, float* smem) {
    float* sWpT = smem;
    float* sH   = smem + HH * 36;
    int tid = threadIdx.x;
    {
        float4 a = ((const float4*)Wp)[tid];
        int e0 = tid * 4;
        int o = e0 >> 5, k = e0 & 31;
        sWpT[(k + 0) * 36 + o] = a.x;
        sWpT[(k + 1) * 36 + o] = a.y;
        sWpT[(k + 2) * 36 + o] = a.z;
        sWpT[(k + 3) * 36 + o] = a.w;
    }
    int g = tid >> 5;
    int n = vb * 8 + g;
    int c = tid & 31;
    int s0 = rs[n], s1 = rs[n + 1];
    float a0 = 0.f, a1 = 0.f, a2 = 0.f, a3 = 0.f;
    int j = s0;
    for (; j + 3 < s1; j += 4) {
        int i0 = csr[j], i1 = csr[j + 1], i2 = csr[j + 2], i3 = csr[j + 3];
        a0 += S[(size_t)i0 * HH + c];
        a1 += S[(size_t)i1 * HH + c];
        a2 += S[(size_t)i2 * HH + c];
        a3 += S[(size_t)i3 * HH + c];
    }
    for (; j < s1; ++j) a0 += S[(size_t)csr[j] * HH + c];
    float acc = (a0 + a1) + (a2 + a3);
    float deg = (float)(s1 - s0);
    deg = deg > 1.f ? deg : 1.f;
    float v = acc / deg + R[(size_t)n * HH + c] + b1[c];
    float ss = v * v;
    ss += __shfl_xor(ss, 1);
    ss += __shfl_xor(ss, 2);
    ss += __shfl_xor(ss, 4);
    ss += __shfl_xor(ss, 8);
    ss += __shfl_xor(ss, 16);
    float nrm = sqrtf(ss);
    nrm = nrm > 1e-12f ? nrm : 1e-12f;
    v = v / nrm;
    v = v > 0.f ? v : 0.f;
    sH[g * 36 + c] = v;
    __syncthreads();
    float a2f = bp[c];
#pragma unroll
    for (int k = 0; k < HH; ++k) a2f += sH[g * 36 + k] * sWpT[k * 36 + c];
    float s2 = a2f * a2f;
    s2 += __shfl_xor(s2, 1);
    s2 += __shfl_xor(s2, 2);
    s2 += __shfl_xor(s2, 4);
    s2 += __shfl_xor(s2, 8);
    s2 += __shfl_xor(s2, 16);
    float nrm2 = sqrtf(s2);
    nrm2 = nrm2 > 1e-12f ? nrm2 : 1e-12f;
    out[(size_t)n * HH + c] = a2f / nrm2;
}

__global__ void p4_k(const int* __restrict__ csrU, const int* __restrict__ rsU,
                     const float* __restrict__ Si2, const float* __restrict__ Ru,
                     const float* __restrict__ b1_iu,
                     const float* __restrict__ wp_user, const float* __restrict__ bp_user,
                     const int* __restrict__ csrI, const int* __restrict__ rsI,
                     const float* __restrict__ Su2, const float* __restrict__ Ri,
                     const float* __restrict__ b1_ui,
                     const float* __restrict__ wp_item, const float* __restrict__ bp_item,
                     float* __restrict__ out) {
    __shared__ float smem[HH * 36 + 8 * 36];
    int b = blockIdx.x;
    if (b < G_P0U) {
        pull1f_body(csrU, rsU, Si2, Ru, b1_iu, wp_user, bp_user, out, b, smem);
    } else {
        pull1f_body(csrI, rsI, Su2, Ri, b1_ui, wp_item, bp_item,
                    out + (size_t)NU * HH, b - G_P0U, smem);
    }
}

// ================= host =================

extern "C" void kernel_launch(void* const* d_in, const int* in_sizes, int n_in,
                              void* d_out, int out_size, void* d_ws, size_t ws_size,
                              hipStream_t stream) {
    const float* x_user = (const float*)d_in[0];
    const float* x_item = (const float*)d_in[1];
    const int* eu = (const int*)d_in[2];
    const int* ei = (const int*)d_in[3];
    const float* wl0_ui = (const float*)d_in[4];
    const float* b0_ui  = (const float*)d_in[5];
    const float* wr0_ui = (const float*)d_in[6];
    const float* wl0_iu = (const float*)d_in[7];
    const float* b0_iu  = (const float*)d_in[8];
    const float* wr0_iu = (const float*)d_in[9];
    const float* wl1_ui = (const float*)d_in[10];
    const float* b1_ui  = (const float*)d_in[11];
    const float* wr1_ui = (const float*)d_in[12];
    const float* wl1_iu = (const float*)d_in[13];
    const float* b1_iu  = (const float*)d_in[14];
    const float* wr1_iu = (const float*)d_in[15];
    const float* wp_user = (const float*)d_in[16];
    const float* bp_user = (const float*)d_in[17];
    const float* wp_item = (const float*)d_in[18];
    const float* bp_item = (const float*)d_in[19];
    float* out = (float*)d_out;
    (void)in_sizes; (void)n_in; (void)out_size; (void)ws_size;

    char* base = (char*)d_ws;
    size_t off = 0;
    auto take = [&](size_t bytes) -> size_t {
        size_t o = off;
        off += (bytes + 255) & ~(size_t)255;
        return o;
    };
    size_t o_rsU  = take((size_t)(NU + 1) * 4);
    size_t o_rsI  = take((size_t)(NI + 1) * 4);
    size_t o_cntU = take((size_t)NBU * NCH * 4);
    size_t o_cntI = take((size_t)NBI * NCH * 4);
    size_t o_csrU = take((size_t)NE * 4);
    size_t o_csrI = take((size_t)NE * 4);
    size_t o_Su = take((size_t)NU * HH * 4);
    size_t o_Si = take((size_t)NI * HH * 4);
    size_t o_Ru = take((size_t)NU * HH * 4);   // also partI staging (8B*NE=6.55MB <= 12.8MB)
    size_t o_Ri = take((size_t)NI * HH * 4);
    size_t o_Su2 = take((size_t)NU * HH * 4);  // also partU staging
    size_t o_Si2 = take((size_t)NI * HH * 4);

    int* rsU  = (int*)(base + o_rsU);
    int* rsI  = (int*)(base + o_rsI);
    int* cntU = (int*)(base + o_cntU);
    int* cntI = (int*)(base + o_cntI);
    int* csrU = (int*)(base + o_csrU);
    int* csrI = (int*)(base + o_csrI);
    float* Su = (float*)(base + o_Su);
    float* Si = (float*)(base + o_Si);
    float* Ru = (float*)(base + o_Ru);
    float* Ri = (float*)(base + o_Ri);
    float* Su2 = (float*)(base + o_Su2);
    float* Si2 = (float*)(base + o_Si2);
    int2* partU = (int2*)(base + o_Su2);   // dead before Su2 written
    int2* partI = (int2*)(base + o_Ru);    // dead before Ru written

    // ---- radix CSR build (no global random atomics, no memset) ----
    cnt1_k<<<2 * NCH, 256, 0, stream>>>((const int4*)eu, (const int4*)ei, cntU, cntI);
    scan2_k<<<1, 1024, 0, stream>>>(cntU, NBU * NCH, cntI, NBI * NCH);
    part_k<<<2 * NCH, 256, 0, stream>>>((const int4*)eu, (const int4*)ei,
                                        cntU, cntI, partU, partI);
    build_k<<<NBU + NBI, 1024, 0, stream>>>(partU, partI, cntU, cntI,
                                            rsU, rsI, csrU, csrI);

    // ---- layer-0 projections (register-tiled) ----
    p1_k<<<G_P128U + G_P128I, 256, 0, stream>>>(x_user, x_item, wl0_ui, wr0_iu,
                                                wl0_iu, wr0_ui, Su, Ru, Si, Ri);

    // ---- layer-0 pulls fused with layer-1 projections ----
    p23_k<<<G_P0I + G_P0U, 256, 0, stream>>>(csrI, rsI, Su, Ri, b0_ui, wl1_iu, wr1_ui, Si2,
                                             csrU, rsU, Si, Ru, b0_iu, wl1_ui, wr1_iu, Su2);

    // ---- layer-1 pulls + final projections -> out ----
    p4_k<<<G_P0U + G_P0I, 256, 0, stream>>>(csrU, rsU, Si2, Ru, b1_iu, wp_user, bp_user,
                                            csrI, rsI, Su2, Ri, b1_ui, wp_item, bp_item,
                                            out);
}